// Round 2
// baseline (343.729 us; speedup 1.0000x reference)
//
#include <hip/hip_runtime.h>
#include <stdint.h>

#define DI __device__ __forceinline__

typedef __attribute__((ext_vector_type(8))) short short8;
typedef __attribute__((ext_vector_type(4))) short short4v;
typedef __attribute__((ext_vector_type(4))) float float4v;
typedef __attribute__((ext_vector_type(16))) float float16v;

#define MFMA16(a, b, c) __builtin_amdgcn_mfma_f32_16x16x32_bf16((a), (b), (c), 0, 0, 0)
#define MFMA32(a, b, c) __builtin_amdgcn_mfma_f32_32x32x16_bf16((a), (b), (c), 0, 0, 0)

DI float b2f(short s) {
    uint32_t u = ((uint32_t)(uint16_t)s) << 16;
    float f;
    __builtin_memcpy(&f, &u, 4);
    return f;
}
DI short f2b(float f) {
    uint32_t x;
    __builtin_memcpy(&x, &f, 4);
    x += 0x7fffu + ((x >> 16) & 1u);
    return (short)(uint16_t)(x >> 16);
}

DI float16v zero16() {
    float16v z;
#pragma unroll
    for (int i = 0; i < 16; ++i) z[i] = 0.f;
    return z;
}

// B=64, C=2048, Q=128, D=128. Packed frag layout (16x16x32): frag_id*512 + lane*8 (+j), bf16.
// 16-frag A/B mapping: row = tile*16 + (lane&15), k = ks*32 + (lane>>4)*8 + j.
// 32x32x16 operands are read from the SAME packed frags via:
//   tile16 = tile32*2 + ((lane&31)>>4), ks = kc>>1,
//   laneoff = (((kc&1)*2 + (lane>>5))*16 + (lane&15))*8     (kc = 0..7 over a 128-dim)

// Fused pack of a 32-row slab of src [b][nkc*32][128]:
//  - A-frags (optionally pre-scaled by wm) -> dstA
//  - transposed B-frags (raw values)       -> dstT
//  - row-dot with wv + mask bias           -> dotout
__global__ __launch_bounds__(256) void k_packfuse(const float* __restrict__ src, const float* __restrict__ wm,
                                                  const float* __restrict__ wv, const float* __restrict__ mask,
                                                  short* __restrict__ dstA, short* __restrict__ dstT,
                                                  float* __restrict__ dotout, int nkc) {
    __shared__ float St[32 * 133];
    int t = threadIdx.x, kc = blockIdx.x, b = blockIdx.y;
    int rl = t >> 3, sub = t & 7, dseg = sub * 16;
    int grow = (b * nkc + kc) * 32 + rl;
    const float* p = src + ((size_t)grow << 7) + dseg;
    float4v v[4];
#pragma unroll
    for (int g = 0; g < 4; ++g) v[g] = *(const float4v*)(p + g * 4);
    // row-dot (raw values)
    float s = 0.f;
#pragma unroll
    for (int g = 0; g < 4; ++g) {
        float4v wg = *(const float4v*)(wv + dseg + g * 4);
#pragma unroll
        for (int j = 0; j < 4; ++j) s += v[g][j] * wg[j];
    }
#pragma unroll
    for (int off = 1; off < 8; off <<= 1) s += __shfl_xor(s, off, 64);
    if (sub == 0) dotout[grow] = s + (1.f - mask[grow]) * (-1e30f);
    // stage raw to LDS for transpose
#pragma unroll
    for (int g = 0; g < 4; ++g)
#pragma unroll
        for (int j = 0; j < 4; ++j) St[rl * 133 + dseg + g * 4 + j] = v[g][j];
    // A-frags (scaled by wm if given)
#pragma unroll
    for (int h = 0; h < 2; ++h) {
        int c16 = sub * 2 + h;
        int ks = c16 >> 2, quad = c16 & 3;
        float4v m0 = wm ? *(const float4v*)(wm + c16 * 8) : (float4v){1.f, 1.f, 1.f, 1.f};
        float4v m1 = wm ? *(const float4v*)(wm + c16 * 8 + 4) : (float4v){1.f, 1.f, 1.f, 1.f};
        short8 o;
#pragma unroll
        for (int j = 0; j < 4; ++j) {
            o[j] = f2b(v[h * 2][j] * m0[j]);
            o[4 + j] = f2b(v[h * 2 + 1][j] * m1[j]);
        }
        int tile = b * (nkc * 2) + kc * 2 + (rl >> 4);
        *(short8*)(dstA + ((size_t)(tile * 4 + ks) << 9) + (quad * 16 + (rl & 15)) * 8) = o;
    }
    __syncthreads();
    // transposed B-frags
#pragma unroll
    for (int i = 0; i < 2; ++i) {
        int dt = (t >> 6) + i * 4;
        int lane = t & 63, ln = lane & 15, quad = lane >> 4;
        int d = dt * 16 + ln;
        short8 o;
#pragma unroll
        for (int j = 0; j < 8; ++j) o[j] = f2b(St[(quad * 8 + j) * 133 + d]);
        *(short8*)(dstT + (((size_t)(b * 8 + dt) * nkc + kc) << 9) + lane * 8) = o;
    }
}

// Pack cqa_W [128][512] fp32 -> frags ((nt*4+part)*4+ks).
__global__ __launch_bounds__(256) void k_packW(const float* __restrict__ wsrc, short* __restrict__ dst) {
    int idx = blockIdx.x * 256 + threadIdx.x;  // 8192
    int lane = idx & 63, ks = (idx >> 6) & 3, part = (idx >> 8) & 3, nt = idx >> 10;
    const float* p = wsrc + (size_t)(nt * 16 + (lane & 15)) * 512 + part * 128 + ks * 32 + (lane >> 4) * 8;
    float4v a = *(const float4v*)p, b = *(const float4v*)(p + 4);
    short8 v;
#pragma unroll
    for (int j = 0; j < 4; ++j) {
        v[j] = f2b(a[j]);
        v[4 + j] = f2b(b[j]);
    }
    *(short8*)(dst + (size_t)idx * 8) = v;
}

// Pack cc_W[:, :128] ([128][256] fp32) -> frags (ot*4+ks).
__global__ __launch_bounds__(256) void k_packWc(const float* __restrict__ wsrc, short* __restrict__ dst) {
    int idx = blockIdx.x * 256 + threadIdx.x;  // 2048
    int lane = idx & 63, ks = (idx >> 6) & 3, ot = idx >> 8;
    const float* p = wsrc + (size_t)(ot * 16 + (lane & 15)) * 256 + ks * 32 + (lane >> 4) * 8;
    float4v a = *(const float4v*)p, b = *(const float4v*)(p + 4);
    short8 v;
#pragma unroll
    for (int j = 0; j < 4; ++j) {
        v[j] = f2b(a[j]);
        v[4 + j] = f2b(b[j]);
    }
    *(short8*)(dst + (size_t)idx * 8) = v;
}

// alpha = softmax_q(qf@wp + mask); pooled; pc[b,o] = cc_b[o] + pooled·cc_W[o,128:]
__global__ __launch_bounds__(128) void k_pool(const float* __restrict__ qf, const float* __restrict__ qmask,
                                              const float* __restrict__ wp, const float* __restrict__ ccW,
                                              const float* __restrict__ ccb, float* __restrict__ pc) {
    __shared__ float tmp[128], af[128], pooled[128];
    int b = blockIdx.x, t = threadIdx.x;
    const float* qrow = qf + ((size_t)(b * 128 + t) << 7);
    float s = 0.f;
    for (int d = 0; d < 128; ++d) s += qrow[d] * wp[d];
    s += (1.f - qmask[b * 128 + t]) * (-1e30f);
    tmp[t] = s;
    __syncthreads();
    for (int off = 64; off >= 1; off >>= 1) {
        if (t < off) tmp[t] = fmaxf(tmp[t], tmp[t + off]);
        __syncthreads();
    }
    float m = tmp[0];
    __syncthreads();
    float e = __expf(s - m);
    tmp[t] = e;
    __syncthreads();
    for (int off = 64; off >= 1; off >>= 1) {
        if (t < off) tmp[t] += tmp[t + off];
        __syncthreads();
    }
    af[t] = e / tmp[0];
    __syncthreads();
    float p = 0.f;
    for (int q = 0; q < 128; ++q) p += qf[((size_t)(b * 128 + q) << 7) + t] * af[q];
    pooled[t] = p;
    __syncthreads();
    float acc = ccb[t];
    for (int d = 0; d < 128; ++d) acc += pooled[d] * ccW[t * 256 + 128 + d];
    pc[b * 128 + t] = acc;
}

// T^T partials over a C-half; deterministic fp32, no atomics. grid flat 1024 (XCD-swizzled).
__global__ __launch_bounds__(256) void k_Tacc(const short* __restrict__ vfA, const short* __restrict__ vfT,
                                              const short* __restrict__ qfBW, const float* __restrict__ cvp,
                                              float* __restrict__ Pg, float* __restrict__ Csg) {
    __shared__ short Al[16 * 136];
    __shared__ float Red[4][16][130];
    __shared__ float csred[4][16];
    int tid = threadIdx.x, w = tid >> 6, lane = tid & 63, ln = lane & 15, quad = lane >> 4;
    // swizzle: keep all qt-blocks of one (b,s) on one XCD
    int id = blockIdx.x;
    int xcd = id & 7, k = id >> 3;
    int g = xcd * 16 + (k & 15);  // (b,s) group 0..127
    int qt = k >> 4;
    int b = g & 63, s = g >> 6;
    short8 bq[4];
#pragma unroll
    for (int ks = 0; ks < 4; ++ks) bq[ks] = *(const short8*)(qfBW + (((size_t)(b * 8 + qt) * 4 + ks) << 9) + lane * 8);
    float4v acc[8];
#pragma unroll
    for (int dt = 0; dt < 8; ++dt) acc[dt] = (float4v){0.f, 0.f, 0.f, 0.f};
    float colacc = 0.f;
    for (int it = 0; it < 8; ++it) {
        int cbase = s * 1024 + it * 128 + w * 32;
        int ct = b * 128 + (cbase >> 4);
        float4v ds[2];
        ds[0] = (float4v){0.f, 0.f, 0.f, 0.f};
        ds[1] = (float4v){0.f, 0.f, 0.f, 0.f};
#pragma unroll
        for (int ks = 0; ks < 4; ++ks) {
#pragma unroll
            for (int mt = 0; mt < 2; ++mt) {
                short8 a = *(const short8*)(vfA + (((size_t)(ct + mt) * 4 + ks) << 9) + lane * 8);
                ds[mt] = MFMA16(a, bq[ks], ds[mt]);
            }
        }
#pragma unroll
        for (int mt = 0; mt < 2; ++mt) {
            float4v cv = *(const float4v*)(cvp + b * 2048 + cbase + mt * 16 + quad * 4);
            short4v ev;
#pragma unroll
            for (int r = 0; r < 4; ++r) {
                float e = __expf(ds[mt][r] + cv[r]);
                colacc += e;
                ev[r] = f2b(e);
            }
            *(short4v*)(Al + ln * 136 + w * 32 + mt * 16 + quad * 4) = ev;
        }
        short8 a = *(const short8*)(Al + ln * 136 + w * 32 + quad * 8);
#pragma unroll
        for (int dt = 0; dt < 8; ++dt) {
            short8 bb = *(const short8*)(vfT + (((size_t)(b * 8 + dt) * 64 + s * 32 + it * 4 + w) << 9) + lane * 8);
            acc[dt] = MFMA16(a, bb, acc[dt]);
        }
    }
#pragma unroll
    for (int dt = 0; dt < 8; ++dt)
#pragma unroll
        for (int r = 0; r < 4; ++r) Red[w][quad * 4 + r][dt * 16 + ln] = acc[dt][r];
    float p = colacc;
    p += __shfl_xor(p, 16, 64);
    p += __shfl_xor(p, 32, 64);
    if (lane < 16) csred[w][lane] = p;
    __syncthreads();
    if (tid < 16)
        Csg[((size_t)(s * 64 + b)) * 128 + qt * 16 + tid] =
            csred[0][tid] + csred[1][tid] + csred[2][tid] + csred[3][tid];
    {
        int q = tid >> 4, db = (tid & 15) * 8;
        float4v s0, s1;
#pragma unroll
        for (int j = 0; j < 4; ++j) {
            s0[j] = Red[0][q][db + j] + Red[1][q][db + j] + Red[2][q][db + j] + Red[3][q][db + j];
            s1[j] = Red[0][q][db + 4 + j] + Red[1][q][db + 4 + j] + Red[2][q][db + 4 + j] + Red[3][q][db + 4 + j];
        }
        size_t pb = (((size_t)(s * 64 + b)) * 8 + qt) * 2048 + q * 128 + db;
        *(float4v*)(Pg + pb) = s0;
        *(float4v*)(Pg + pb + 4) = s1;
    }
}

// Combine 2 partials + colsum -> Ttf bf16 B-frags.
__global__ __launch_bounds__(256) void k_Tcomb(const float* __restrict__ Pg, const float* __restrict__ Csg,
                                               short* __restrict__ Ttf) {
    int idx = blockIdx.x * 256 + threadIdx.x;  // 131072
    int lane = idx & 63, dt = (idx >> 8) & 7, b = idx >> 11;
    int d = dt * 16 + (lane & 15), q0 = ((idx >> 6) & 3) * 32 + (lane >> 4) * 8;
    short8 v;
#pragma unroll
    for (int j = 0; j < 8; ++j) {
        int q = q0 + j;
        size_t o0 = ((size_t)(b * 8) + (q >> 4)) * 2048 + (q & 15) * 128 + d;
        size_t o1 = ((size_t)((64 + b) * 8) + (q >> 4)) * 2048 + (q & 15) * 128 + d;
        float pv = Pg[o0] + Pg[o1];
        float cs = Csg[b * 128 + q] + Csg[(64 + b) * 128 + q];
        v[j] = f2b(pv / cs);
    }
    *(short8*)(Ttf + (size_t)idx * 8) = v;
}

// -------------------- 32x32x16 mega kernel --------------------
// All-transposed schedule, zero barriers, wave-private 32-c-column tile.
//   scoreT = mfma(A = w∘q [qfBW], B = v^T [vfA-as-B])      D: row=q, col=c
//   softmax over q: 64 in-reg values/lane + one shfl_xor(32)
//   P^T B-frags via per-column LDS round trip (lane-pair l <-> l^32 only)
//   c2qT = mfma(A = Q^T [qTf], B = P^T)                    -> B-frags cb
//   q2cT = mfma(A = T^T [Ttf], B = P^T)                    -> B-frags qb
//   featsT = mfma(A = cqa_W [cqaWp], B = catT parts)       -> A-frags fa (+bias)
//   out = mfma(A = feats, B = ccW^T [ccWp]) + pc, relu     D: row=c, col=o (coalesced)
__global__ __launch_bounds__(256, 3) void k_out32(const short* __restrict__ vfA, const short* __restrict__ qfBW,
                                                  const short* __restrict__ qTf, const short* __restrict__ Ttf,
                                                  const float* __restrict__ qvp, const short* __restrict__ cqaWp,
                                                  const float* __restrict__ cqab, const short* __restrict__ ccWp,
                                                  const float* __restrict__ pc, float* __restrict__ out) {
    __shared__ __align__(16) short Pl[4][32 * 132];  // per-wave transpose scratch, stride 132 (2-way banks only)
    int tid = threadIdx.x, w = tid >> 6, l = tid & 63;
    int h = l >> 5, c5 = l & 31, ln = c5 & 15, tadd = c5 >> 4;
    // swizzle: all c-tiles of one b on one XCD
    int id = blockIdx.x;
    int xcd = id & 7, kk = id >> 3;
    int b = xcd * 8 + (kk & 7);
    int cblk = kk >> 3;       // 0..15
    int ct2 = cblk * 4 + w;   // c 32-tile, 0..63
    int c0 = ct2 * 32;
    short* myP = Pl[w];
    int col = c5 * 132;
    // lane byte-offsets into a packed 16-frag for the 32-operand read
    int loff0 = (h * 16 + ln) * 8;
    int loff1 = ((2 + h) * 16 + ln) * 8;
    int vbase = b * 128 + ct2 * 2 + tadd;  // vfA tile16 (B-side, col=c)

#define FR32(p, t16, kc) \
    (*(const short8*)((p) + (((size_t)(t16) * 4 + ((kc) >> 1)) << 9) + (((kc)&1) ? loff1 : loff0)))

    // ---- phase 1: scoreT (row=q, col=c) ----
    float16v sc[4];
#pragma unroll
    for (int qt2 = 0; qt2 < 4; ++qt2) sc[qt2] = zero16();
#pragma unroll
    for (int kc = 0; kc < 8; ++kc) {
        short8 bv = FR32(vfA, vbase, kc);
#pragma unroll
        for (int qt2 = 0; qt2 < 4; ++qt2) {
            short8 aq = FR32(qfBW, b * 8 + qt2 * 2 + tadd, kc);
            sc[qt2] = MFMA32(aq, bv, sc[qt2]);
        }
    }
    // ---- softmax over q (bias qvp[q]; per-c constant cvp cancels) ----
    float m = -3.4e38f;
#pragma unroll
    for (int qt2 = 0; qt2 < 4; ++qt2)
#pragma unroll
        for (int g = 0; g < 4; ++g) {
            float4v qv = *(const float4v*)(qvp + b * 128 + qt2 * 32 + g * 8 + 4 * h);
#pragma unroll
            for (int r = 0; r < 4; ++r) {
                float xv = sc[qt2][g * 4 + r] + qv[r];
                sc[qt2][g * 4 + r] = xv;
                m = fmaxf(m, xv);
            }
        }
    m = fmaxf(m, __shfl_xor(m, 32, 64));
    float sm = 0.f;
#pragma unroll
    for (int qt2 = 0; qt2 < 4; ++qt2)
#pragma unroll
        for (int i = 0; i < 16; ++i) {
            float e = __expf(sc[qt2][i] - m);
            sc[qt2][i] = e;
            sm += e;
        }
    sm += __shfl_xor(sm, 32, 64);
    float inv = 1.f / sm;
    // ---- P^T -> LDS (own column) -> B-frags pb ----
#pragma unroll
    for (int qt2 = 0; qt2 < 4; ++qt2)
#pragma unroll
        for (int g = 0; g < 4; ++g) {
            short4v o;
#pragma unroll
            for (int r = 0; r < 4; ++r) o[r] = f2b(sc[qt2][g * 4 + r] * inv);
            *(short4v*)(myP + col + qt2 * 32 + g * 8 + 4 * h) = o;
        }
    short8 pb[8];
#pragma unroll
    for (int kc = 0; kc < 8; ++kc) {
        short4v lo = *(const short4v*)(myP + col + kc * 16 + h * 8);
        short4v hi = *(const short4v*)(myP + col + kc * 16 + h * 8 + 4);
        short8 p8;
#pragma unroll
        for (int j = 0; j < 4; ++j) {
            p8[j] = lo[j];
            p8[4 + j] = hi[j];
        }
        pb[kc] = p8;
    }
    // ---- phase 2: c2qT (row=d, col=c) ----
    float16v cq[4];
#pragma unroll
    for (int dt2 = 0; dt2 < 4; ++dt2) cq[dt2] = zero16();
#pragma unroll
    for (int kc = 0; kc < 8; ++kc)
#pragma unroll
        for (int dt2 = 0; dt2 < 4; ++dt2) {
            short8 a = FR32(qTf, b * 8 + dt2 * 2 + tadd, kc);
            cq[dt2] = MFMA32(a, pb[kc], cq[dt2]);
        }
    // convert -> B-frags cb
    short8 cb[8];
#pragma unroll
    for (int dt2 = 0; dt2 < 4; ++dt2)
#pragma unroll
        for (int g = 0; g < 4; ++g) {
            short4v o;
#pragma unroll
            for (int r = 0; r < 4; ++r) o[r] = f2b(cq[dt2][g * 4 + r]);
            *(short4v*)(myP + col + dt2 * 32 + g * 8 + 4 * h) = o;
        }
#pragma unroll
    for (int kc = 0; kc < 8; ++kc) {
        short4v lo = *(const short4v*)(myP + col + kc * 16 + h * 8);
        short4v hi = *(const short4v*)(myP + col + kc * 16 + h * 8 + 4);
        short8 p8;
#pragma unroll
        for (int j = 0; j < 4; ++j) {
            p8[j] = lo[j];
            p8[4 + j] = hi[j];
        }
        cb[kc] = p8;
    }
    // ---- phase 3: q2cT (row=d, col=c); pb reused, dead after ----
    float16v qc[4];
#pragma unroll
    for (int dt2 = 0; dt2 < 4; ++dt2) qc[dt2] = zero16();
#pragma unroll
    for (int kc = 0; kc < 8; ++kc)
#pragma unroll
        for (int dt2 = 0; dt2 < 4; ++dt2) {
            short8 a = FR32(Ttf, b * 8 + dt2 * 2 + tadd, kc);
            qc[dt2] = MFMA32(a, pb[kc], qc[dt2]);
        }
    short8 qb[8];
#pragma unroll
    for (int dt2 = 0; dt2 < 4; ++dt2)
#pragma unroll
        for (int g = 0; g < 4; ++g) {
            short4v o;
#pragma unroll
            for (int r = 0; r < 4; ++r) o[r] = f2b(qc[dt2][g * 4 + r]);
            *(short4v*)(myP + col + dt2 * 32 + g * 8 + 4 * h) = o;
        }
#pragma unroll
    for (int kc = 0; kc < 8; ++kc) {
        short4v lo = *(const short4v*)(myP + col + kc * 16 + h * 8);
        short4v hi = *(const short4v*)(myP + col + kc * 16 + h * 8 + 4);
        short8 p8;
#pragma unroll
        for (int j = 0; j < 4; ++j) {
            p8[j] = lo[j];
            p8[4 + j] = hi[j];
        }
        qb[kc] = p8;
    }
    // ---- phase 4: featsT = [v, c2q, v∘c2q, v∘q2c]^T @ ... = mfma(A=W, B=catT) ----
    float16v ft[4];
#pragma unroll
    for (int nt2 = 0; nt2 < 4; ++nt2) ft[nt2] = zero16();
#pragma unroll
    for (int kc = 0; kc < 8; ++kc) {
        short8 vb = FR32(vfA, vbase, kc);
        short8 pcb, pqb;
#pragma unroll
        for (int j = 0; j < 8; ++j) {
            float fv = b2f(vb[j]);
            pcb[j] = f2b(fv * b2f(cb[kc][j]));
            pqb[j] = f2b(fv * b2f(qb[kc][j]));
        }
#pragma unroll
        for (int part = 0; part < 4; ++part) {
            short8 pB = (part == 0) ? vb : (part == 1) ? cb[kc] : (part == 2) ? pcb : pqb;
#pragma unroll
            for (int nt2 = 0; nt2 < 4; ++nt2) {
                short8 aw = FR32(cqaWp, (nt2 * 2 + tadd) * 4 + part, kc);
                ft[nt2] = MFMA32(aw, pB, ft[nt2]);
            }
        }
    }
    // ---- feats (+bias) -> A-frags fa ----
#pragma unroll
    for (int nt2 = 0; nt2 < 4; ++nt2)
#pragma unroll
        for (int g = 0; g < 4; ++g) {
            float4v bj = *(const float4v*)(cqab + nt2 * 32 + g * 8 + 4 * h);
            short4v o;
#pragma unroll
            for (int r = 0; r < 4; ++r) o[r] = f2b(ft[nt2][g * 4 + r] + bj[r]);
            *(short4v*)(myP + col + nt2 * 32 + g * 8 + 4 * h) = o;
        }
    short8 fa[8];
#pragma unroll
    for (int kc = 0; kc < 8; ++kc) {
        short4v lo = *(const short4v*)(myP + col + kc * 16 + h * 8);
        short4v hi = *(const short4v*)(myP + col + kc * 16 + h * 8 + 4);
        short8 p8;
#pragma unroll
        for (int j = 0; j < 4; ++j) {
            p8[j] = lo[j];
            p8[4 + j] = hi[j];
        }
        fa[kc] = p8;
    }
    // ---- phase 5: out = relu(feats @ ccW[:, :128].T + pc); D: row=c, col=o ----
    float16v ao[4];
#pragma unroll
    for (int ot2 = 0; ot2 < 4; ++ot2) ao[ot2] = zero16();
#pragma unroll
    for (int kc = 0; kc < 8; ++kc)
#pragma unroll
        for (int ot2 = 0; ot2 < 4; ++ot2) {
            short8 bw = FR32(ccWp, ot2 * 2 + tadd, kc);
            ao[ot2] = MFMA32(fa[kc], bw, ao[ot2]);
        }
#pragma unroll
    for (int ot2 = 0; ot2 < 4; ++ot2) {
        float pco = pc[b * 128 + ot2 * 32 + c5];
#pragma unroll
        for (int i = 0; i < 16; ++i) {
            int c = c0 + (i & 3) + 8 * (i >> 2) + 4 * h;
            out[((size_t)(b * 2048 + c) << 7) + ot2 * 32 + c5] = fmaxf(ao[ot2][i] + pco, 0.f);
        }
    }
#undef FR32
}

extern "C" void kernel_launch(void* const* d_in, const int* in_sizes, int n_in, void* d_out, int out_size, void* d_ws,
                              size_t ws_size, hipStream_t stream) {
    const float* vf = (const float*)d_in[0];
    const float* qf = (const float*)d_in[1];
    const float* vmask = (const float*)d_in[2];
    const float* qmask = (const float*)d_in[3];
    const float* w4C = (const float*)d_in[4];
    const float* w4Q = (const float*)d_in[5];
    const float* w4mlu = (const float*)d_in[6];
    const float* cqaW = (const float*)d_in[7];
    const float* cqab = (const float*)d_in[8];
    const float* wp = (const float*)d_in[9];
    const float* ccW = (const float*)d_in[10];
    const float* ccb = (const float*)d_in[11];
    float* out = (float*)d_out;
    char* ws = (char*)d_ws;

    // workspace layout (~83 MB)
    size_t o = 0;
    short* vfA = (short*)(ws + o); o += 64ull * 2048 * 128 * 2;   // 33.5 MB
    short* vfT = (short*)(ws + o); o += 64ull * 2048 * 128 * 2;   // 33.5 MB
    short* qfBW = (short*)(ws + o); o += 64ull * 128 * 128 * 2;   // 2 MB
    short* qTf = (short*)(ws + o); o += 64ull * 128 * 128 * 2;    // 2 MB
    short* Ttf = (short*)(ws + o); o += 64ull * 128 * 128 * 2;    // 2 MB
    short* cqaWp = (short*)(ws + o); o += 128ull * 512 * 2;       // 128 KB
    short* ccWp = (short*)(ws + o); o += 128ull * 128 * 2;        // 32 KB
    float* Pg = (float*)(ws + o); o += 2ull * 64 * 128 * 128 * 4; // 8.4 MB
    float* Csg = (float*)(ws + o); o += 2ull * 64 * 128 * 4;      // 64 KB
    float* cvp = (float*)(ws + o); o += 64ull * 2048 * 4;         // 512 KB
    float* qvp = (float*)(ws + o); o += 64ull * 128 * 4;
    float* pc = (float*)(ws + o); o += 64ull * 128 * 4;

    k_packfuse<<<dim3(64, 64), 256, 0, stream>>>(vf, nullptr, w4C, vmask, vfA, vfT, cvp, 64);
    k_packfuse<<<dim3(4, 64), 256, 0, stream>>>(qf, w4mlu, w4Q, qmask, qfBW, qTf, qvp, 4);
    k_packW<<<32, 256, 0, stream>>>(cqaW, cqaWp);
    k_packWc<<<8, 256, 0, stream>>>(ccW, ccWp);
    k_pool<<<64, 128, 0, stream>>>(qf, qmask, wp, ccW, ccb, pc);
    k_Tacc<<<1024, 256, 0, stream>>>(vfA, vfT, qfBW, cvp, Pg, Csg);
    k_Tcomb<<<512, 256, 0, stream>>>(Pg, Csg, Ttf);
    k_out32<<<1024, 256, 0, stream>>>(vfA, qfBW, qTf, Ttf, qvp, cqaWp, cqab, ccWp, pc, out);
}

// Round 3
// 264.497 us; speedup vs baseline: 1.2996x; 1.2996x over previous
//
#include <hip/hip_runtime.h>
#include <stdint.h>

#define DI __device__ __forceinline__

typedef __attribute__((ext_vector_type(8))) short short8;
typedef __attribute__((ext_vector_type(4))) short short4v;
typedef __attribute__((ext_vector_type(4))) float float4v;

#define MFMA16(a, b, c) __builtin_amdgcn_mfma_f32_16x16x32_bf16((a), (b), (c), 0, 0, 0)

DI float b2f(short s) {
    uint32_t u = ((uint32_t)(uint16_t)s) << 16;
    float f;
    __builtin_memcpy(&f, &u, 4);
    return f;
}
DI short f2b(float f) {
    uint32_t x;
    __builtin_memcpy(&x, &f, 4);
    x += 0x7fffu + ((x >> 16) & 1u);
    return (short)(uint16_t)(x >> 16);
}

// B=64, C=2048, Q=128, D=128. Frag layout: frag_id*512 + lane*8 (+j), bf16.
// A/B frag mapping: row = tile*16 + (lane&15), col(k) = ks*32 + (lane>>4)*8 + j.

// Fused pack of a 32-row slab of src [b][nkc*32][128]:
//  - A-frags (optionally pre-scaled by wm) -> dstA
//  - transposed B-frags (raw values)       -> dstT
//  - row-dot with wv + mask bias           -> dotout
__global__ __launch_bounds__(256) void k_packfuse(const float* __restrict__ src, const float* __restrict__ wm,
                                                  const float* __restrict__ wv, const float* __restrict__ mask,
                                                  short* __restrict__ dstA, short* __restrict__ dstT,
                                                  float* __restrict__ dotout, int nkc) {
    __shared__ float St[32 * 133];
    int t = threadIdx.x, kc = blockIdx.x, b = blockIdx.y;
    int rl = t >> 3, sub = t & 7, dseg = sub * 16;
    int grow = (b * nkc + kc) * 32 + rl;
    const float* p = src + ((size_t)grow << 7) + dseg;
    float4v v[4];
#pragma unroll
    for (int g = 0; g < 4; ++g) v[g] = *(const float4v*)(p + g * 4);
    // row-dot (raw values)
    float s = 0.f;
#pragma unroll
    for (int g = 0; g < 4; ++g) {
        float4v wg = *(const float4v*)(wv + dseg + g * 4);
#pragma unroll
        for (int j = 0; j < 4; ++j) s += v[g][j] * wg[j];
    }
#pragma unroll
    for (int off = 1; off < 8; off <<= 1) s += __shfl_xor(s, off, 64);
    if (sub == 0) dotout[grow] = s + (1.f - mask[grow]) * (-1e30f);
    // stage raw to LDS for transpose
#pragma unroll
    for (int g = 0; g < 4; ++g)
#pragma unroll
        for (int j = 0; j < 4; ++j) St[rl * 133 + dseg + g * 4 + j] = v[g][j];
    // A-frags (scaled by wm if given)
#pragma unroll
    for (int h = 0; h < 2; ++h) {
        int c16 = sub * 2 + h;
        int ks = c16 >> 2, quad = c16 & 3;
        float4v m0 = wm ? *(const float4v*)(wm + c16 * 8) : (float4v){1.f, 1.f, 1.f, 1.f};
        float4v m1 = wm ? *(const float4v*)(wm + c16 * 8 + 4) : (float4v){1.f, 1.f, 1.f, 1.f};
        short8 o;
#pragma unroll
        for (int j = 0; j < 4; ++j) {
            o[j] = f2b(v[h * 2][j] * m0[j]);
            o[4 + j] = f2b(v[h * 2 + 1][j] * m1[j]);
        }
        int tile = b * (nkc * 2) + kc * 2 + (rl >> 4);
        *(short8*)(dstA + ((size_t)(tile * 4 + ks) << 9) + (quad * 16 + (rl & 15)) * 8) = o;
    }
    __syncthreads();
    // transposed B-frags
#pragma unroll
    for (int i = 0; i < 2; ++i) {
        int dt = (t >> 6) + i * 4;
        int lane = t & 63, ln = lane & 15, quad = lane >> 4;
        int d = dt * 16 + ln;
        short8 o;
#pragma unroll
        for (int j = 0; j < 8; ++j) o[j] = f2b(St[(quad * 8 + j) * 133 + d]);
        *(short8*)(dstT + (((size_t)(b * 8 + dt) * nkc + kc) << 9) + lane * 8) = o;
    }
}

// Pack cqa_W [128][512] fp32 -> frags ((nt*4+part)*4+ks).
__global__ __launch_bounds__(256) void k_packW(const float* __restrict__ wsrc, short* __restrict__ dst) {
    int idx = blockIdx.x * 256 + threadIdx.x;  // 8192
    int lane = idx & 63, ks = (idx >> 6) & 3, part = (idx >> 8) & 3, nt = idx >> 10;
    const float* p = wsrc + (size_t)(nt * 16 + (lane & 15)) * 512 + part * 128 + ks * 32 + (lane >> 4) * 8;
    float4v a = *(const float4v*)p, b = *(const float4v*)(p + 4);
    short8 v;
#pragma unroll
    for (int j = 0; j < 4; ++j) {
        v[j] = f2b(a[j]);
        v[4 + j] = f2b(b[j]);
    }
    *(short8*)(dst + (size_t)idx * 8) = v;
}

// Pack cc_W[:, :128] ([128][256] fp32) -> frags (ot*4+ks).
__global__ __launch_bounds__(256) void k_packWc(const float* __restrict__ wsrc, short* __restrict__ dst) {
    int idx = blockIdx.x * 256 + threadIdx.x;  // 2048
    int lane = idx & 63, ks = (idx >> 6) & 3, ot = idx >> 8;
    const float* p = wsrc + (size_t)(ot * 16 + (lane & 15)) * 256 + ks * 32 + (lane >> 4) * 8;
    float4v a = *(const float4v*)p, b = *(const float4v*)(p + 4);
    short8 v;
#pragma unroll
    for (int j = 0; j < 4; ++j) {
        v[j] = f2b(a[j]);
        v[4 + j] = f2b(b[j]);
    }
    *(short8*)(dst + (size_t)idx * 8) = v;
}

// alpha = softmax_q(qf@wp + mask); pooled; pc[b,o] = cc_b[o] + pooled·cc_W[o,128:]
__global__ __launch_bounds__(128) void k_pool(const float* __restrict__ qf, const float* __restrict__ qmask,
                                              const float* __restrict__ wp, const float* __restrict__ ccW,
                                              const float* __restrict__ ccb, float* __restrict__ pc) {
    __shared__ float tmp[128], af[128], pooled[128];
    int b = blockIdx.x, t = threadIdx.x;
    const float* qrow = qf + ((size_t)(b * 128 + t) << 7);
    float s = 0.f;
    for (int d = 0; d < 128; ++d) s += qrow[d] * wp[d];
    s += (1.f - qmask[b * 128 + t]) * (-1e30f);
    tmp[t] = s;
    __syncthreads();
    for (int off = 64; off >= 1; off >>= 1) {
        if (t < off) tmp[t] = fmaxf(tmp[t], tmp[t + off]);
        __syncthreads();
    }
    float m = tmp[0];
    __syncthreads();
    float e = __expf(s - m);
    tmp[t] = e;
    __syncthreads();
    for (int off = 64; off >= 1; off >>= 1) {
        if (t < off) tmp[t] += tmp[t + off];
        __syncthreads();
    }
    af[t] = e / tmp[0];
    __syncthreads();
    float p = 0.f;
    for (int q = 0; q < 128; ++q) p += qf[((size_t)(b * 128 + q) << 7) + t] * af[q];
    pooled[t] = p;
    __syncthreads();
    float acc = ccb[t];
    for (int d = 0; d < 128; ++d) acc += pooled[d] * ccW[t * 256 + 128 + d];
    pc[b * 128 + t] = acc;
}

// T^T partials over a C-half; deterministic fp32, no atomics. grid flat 1024 (XCD-swizzled).
__global__ __launch_bounds__(256) void k_Tacc(const short* __restrict__ vfA, const short* __restrict__ vfT,
                                              const short* __restrict__ qfBW, const float* __restrict__ cvp,
                                              float* __restrict__ Pg, float* __restrict__ Csg) {
    __shared__ short Al[16 * 136];
    __shared__ float Red[4][16][130];
    __shared__ float csred[4][16];
    int tid = threadIdx.x, w = tid >> 6, lane = tid & 63, ln = lane & 15, quad = lane >> 4;
    // swizzle: keep all qt-blocks of one (b,s) on one XCD
    int id = blockIdx.x;
    int xcd = id & 7, k = id >> 3;
    int g = xcd * 16 + (k & 15);  // (b,s) group 0..127
    int qt = k >> 4;
    int b = g & 63, s = g >> 6;
    short8 bq[4];
#pragma unroll
    for (int ks = 0; ks < 4; ++ks) bq[ks] = *(const short8*)(qfBW + (((size_t)(b * 8 + qt) * 4 + ks) << 9) + lane * 8);
    float4v acc[8];
#pragma unroll
    for (int dt = 0; dt < 8; ++dt) acc[dt] = (float4v){0.f, 0.f, 0.f, 0.f};
    float colacc = 0.f;
    for (int it = 0; it < 8; ++it) {
        int cbase = s * 1024 + it * 128 + w * 32;
        int ct = b * 128 + (cbase >> 4);
        float4v ds[2];
        ds[0] = (float4v){0.f, 0.f, 0.f, 0.f};
        ds[1] = (float4v){0.f, 0.f, 0.f, 0.f};
#pragma unroll
        for (int ks = 0; ks < 4; ++ks) {
#pragma unroll
            for (int mt = 0; mt < 2; ++mt) {
                short8 a = *(const short8*)(vfA + (((size_t)(ct + mt) * 4 + ks) << 9) + lane * 8);
                ds[mt] = MFMA16(a, bq[ks], ds[mt]);
            }
        }
#pragma unroll
        for (int mt = 0; mt < 2; ++mt) {
            float4v cv = *(const float4v*)(cvp + b * 2048 + cbase + mt * 16 + quad * 4);
            short4v ev;
#pragma unroll
            for (int r = 0; r < 4; ++r) {
                float e = __expf(ds[mt][r] + cv[r]);
                colacc += e;
                ev[r] = f2b(e);
            }
            *(short4v*)(Al + ln * 136 + w * 32 + mt * 16 + quad * 4) = ev;
        }
        short8 a = *(const short8*)(Al + ln * 136 + w * 32 + quad * 8);
#pragma unroll
        for (int dt = 0; dt < 8; ++dt) {
            short8 bb = *(const short8*)(vfT + (((size_t)(b * 8 + dt) * 64 + s * 32 + it * 4 + w) << 9) + lane * 8);
            acc[dt] = MFMA16(a, bb, acc[dt]);
        }
    }
#pragma unroll
    for (int dt = 0; dt < 8; ++dt)
#pragma unroll
        for (int r = 0; r < 4; ++r) Red[w][quad * 4 + r][dt * 16 + ln] = acc[dt][r];
    float p = colacc;
    p += __shfl_xor(p, 16, 64);
    p += __shfl_xor(p, 32, 64);
    if (lane < 16) csred[w][lane] = p;
    __syncthreads();
    if (tid < 16)
        Csg[((size_t)(s * 64 + b)) * 128 + qt * 16 + tid] =
            csred[0][tid] + csred[1][tid] + csred[2][tid] + csred[3][tid];
    {
        int q = tid >> 4, db = (tid & 15) * 8;
        float4v s0, s1;
#pragma unroll
        for (int j = 0; j < 4; ++j) {
            s0[j] = Red[0][q][db + j] + Red[1][q][db + j] + Red[2][q][db + j] + Red[3][q][db + j];
            s1[j] = Red[0][q][db + 4 + j] + Red[1][q][db + 4 + j] + Red[2][q][db + 4 + j] + Red[3][q][db + 4 + j];
        }
        size_t pb = (((size_t)(s * 64 + b)) * 8 + qt) * 2048 + q * 128 + db;
        *(float4v*)(Pg + pb) = s0;
        *(float4v*)(Pg + pb + 4) = s1;
    }
}

// Combine 2 partials + colsum -> Ttf bf16 B-frags.
__global__ __launch_bounds__(256) void k_Tcomb(const float* __restrict__ Pg, const float* __restrict__ Csg,
                                               short* __restrict__ Ttf) {
    int idx = blockIdx.x * 256 + threadIdx.x;  // 131072
    int lane = idx & 63, dt = (idx >> 8) & 7, b = idx >> 11;
    int d = dt * 16 + (lane & 15), q0 = ((idx >> 6) & 3) * 32 + (lane >> 4) * 8;
    short8 v;
#pragma unroll
    for (int j = 0; j < 8; ++j) {
        int q = q0 + j;
        size_t o0 = ((size_t)(b * 8) + (q >> 4)) * 2048 + (q & 15) * 128 + d;
        size_t o1 = ((size_t)((64 + b) * 8) + (q >> 4)) * 2048 + (q & 15) * 128 + d;
        float pv = Pg[o0] + Pg[o1];
        float cs = Csg[b * 128 + q] + Csg[(64 + b) * 128 + q];
        v[j] = f2b(pv / cs);
    }
    *(short8*)(Ttf + (size_t)idx * 8) = v;
}

// Mega kernel. Phases 1-3 (score/softmax/c2q/q2c) are wave-private, as in the
// proven 94 µs version. Cat + out GEMMs are N-SPLIT across the 4 waves: each
// wave computes output-column slice {2w,2w+1} for ALL 64 c-rows of the block,
// reading A-frags from the shared Sl/Xl arrays. This loads each cqa_W / cc_W
// fragment ONCE per block instead of 4x -> per-block L2 traffic 1.04 MB -> 0.62 MB.
// grid flat 2048 (XCD-swizzled), 256 thr, 3 barriers.
__global__ __launch_bounds__(256, 4) void k_out(const short* __restrict__ vfA, const short* __restrict__ qfBW,
                                                const short* __restrict__ qTf, const short* __restrict__ Ttf,
                                                const float* __restrict__ qvp, const short* __restrict__ cqaWp,
                                                const float* __restrict__ cqab, const short* __restrict__ ccWp,
                                                const float* __restrict__ pc, float* __restrict__ out) {
    __shared__ short Sl[64 * 136];  // score_ -> q2c -> feats
    __shared__ short Xl[64 * 136];  // c2q
    int tid = threadIdx.x, w = tid >> 6, lane = tid & 63, ln = lane & 15, quad = lane >> 4;
    // swizzle: all c-tiles of one b on one XCD
    int id = blockIdx.x;
    int xcd = id & 7, k = id >> 3;
    int b = xcd * 8 + (k & 7);
    int cx = k >> 3;
    int c0 = cx * 64 + w * 16;
    int tt = b * 128 + (c0 >> 4);
    int myrow = (w * 16 + ln) * 136;
    // ---- score tile: 16c x 128q (A = raw v, B = w∘q) ----
    {
        float4v sc[8];
#pragma unroll
        for (int qt = 0; qt < 8; ++qt) sc[qt] = (float4v){0.f, 0.f, 0.f, 0.f};
#pragma unroll
        for (int ks = 0; ks < 4; ++ks) {
            short8 av = *(const short8*)(vfA + (((size_t)tt * 4 + ks) << 9) + lane * 8);
#pragma unroll
            for (int qt = 0; qt < 8; ++qt) {
                short8 bq = *(const short8*)(qfBW + (((size_t)(b * 8 + qt) * 4 + ks) << 9) + lane * 8);
                sc[qt] = MFMA16(av, bq, sc[qt]);
            }
        }
        float qvl[8];
#pragma unroll
        for (int qt = 0; qt < 8; ++qt) qvl[qt] = qvp[b * 128 + qt * 16 + ln];
        // ---- row softmax over q ----
#pragma unroll
        for (int r = 0; r < 4; ++r) {
            float x[8], m = -3.4e38f;
#pragma unroll
            for (int qt = 0; qt < 8; ++qt) {
                x[qt] = sc[qt][r] + qvl[qt];
                m = fmaxf(m, x[qt]);
            }
#pragma unroll
            for (int off = 1; off < 16; off <<= 1) m = fmaxf(m, __shfl_xor(m, off, 64));
            float e[8], sm = 0.f;
#pragma unroll
            for (int qt = 0; qt < 8; ++qt) {
                e[qt] = __expf(x[qt] - m);
                sm += e[qt];
            }
#pragma unroll
            for (int off = 1; off < 16; off <<= 1) sm += __shfl_xor(sm, off, 64);
            float inv = 1.f / sm;
            int row = (w * 16 + quad * 4 + r) * 136;
#pragma unroll
            for (int qt = 0; qt < 8; ++qt) Sl[row + qt * 16 + ln] = f2b(e[qt] * inv);
        }
    }
    // ---- c2q = score_ @ qf -> Xl ----
    {
        float4v a2q[8];
#pragma unroll
        for (int dt = 0; dt < 8; ++dt) a2q[dt] = (float4v){0.f, 0.f, 0.f, 0.f};
#pragma unroll
        for (int ks = 0; ks < 4; ++ks) {
            short8 a = *(const short8*)(Sl + myrow + ks * 32 + quad * 8);
#pragma unroll
            for (int dt = 0; dt < 8; ++dt) {
                short8 b1 = *(const short8*)(qTf + (((size_t)(b * 8 + dt) * 4 + ks) << 9) + lane * 8);
                a2q[dt] = MFMA16(a, b1, a2q[dt]);
            }
        }
#pragma unroll
        for (int dt = 0; dt < 8; ++dt)
#pragma unroll
            for (int r = 0; r < 4; ++r) Xl[(w * 16 + quad * 4 + r) * 136 + dt * 16 + ln] = f2b(a2q[dt][r]);
    }
    // ---- q2c = score_ @ T -> Sl (score_ dead afterwards; wave-private rows) ----
    {
        float4v aq2[8];
#pragma unroll
        for (int dt = 0; dt < 8; ++dt) aq2[dt] = (float4v){0.f, 0.f, 0.f, 0.f};
#pragma unroll
        for (int ks = 0; ks < 4; ++ks) {
            short8 a = *(const short8*)(Sl + myrow + ks * 32 + quad * 8);
#pragma unroll
            for (int dt = 0; dt < 8; ++dt) {
                short8 b2 = *(const short8*)(Ttf + (((size_t)(b * 8 + dt) * 4 + ks) << 9) + lane * 8);
                aq2[dt] = MFMA16(a, b2, aq2[dt]);
            }
        }
#pragma unroll
        for (int dt = 0; dt < 8; ++dt)
#pragma unroll
            for (int r = 0; r < 4; ++r) Sl[(w * 16 + quad * 4 + r) * 136 + dt * 16 + ln] = f2b(aq2[dt][r]);
    }
    __syncthreads();  // barrier1: Sl(q2c) + Xl(c2q) complete for all waves
    // ---- cat GEMM, N-split: wave w -> nt {2w, 2w+1}, all 64 c-rows ----
    float4v accF[4][2];
#pragma unroll
    for (int ct = 0; ct < 4; ++ct)
#pragma unroll
        for (int nt2 = 0; nt2 < 2; ++nt2) accF[ct][nt2] = (float4v){0.f, 0.f, 0.f, 0.f};
#pragma unroll
    for (int ks = 0; ks < 4; ++ks) {
        short8 avk[4];
#pragma unroll
        for (int ct = 0; ct < 4; ++ct)
            avk[ct] = *(const short8*)(vfA + (((size_t)(b * 128 + cx * 4 + ct) * 4 + ks) << 9) + lane * 8);
#pragma unroll
        for (int part = 0; part < 4; ++part) {
            short8 a[4];
#pragma unroll
            for (int ct = 0; ct < 4; ++ct) {
                int rowo = (ct * 16 + ln) * 136 + ks * 32 + quad * 8;
                if (part == 0) {
                    a[ct] = avk[ct];
                } else if (part == 1) {
                    a[ct] = *(const short8*)(Xl + rowo);
                } else {
                    short8 mfr = (part == 2) ? *(const short8*)(Xl + rowo) : *(const short8*)(Sl + rowo);
#pragma unroll
                    for (int j = 0; j < 8; ++j) a[ct][j] = f2b(b2f(avk[ct][j]) * b2f(mfr[j]));
                }
            }
#pragma unroll
            for (int nt2 = 0; nt2 < 2; ++nt2) {
                short8 bw =
                    *(const short8*)(cqaWp + (((size_t)((w * 2 + nt2) * 4 + part) * 4 + ks) << 9) + lane * 8);
#pragma unroll
                for (int ct = 0; ct < 4; ++ct) accF[ct][nt2] = MFMA16(a[ct], bw, accF[ct][nt2]);
            }
        }
    }
    __syncthreads();  // barrier2: all waves done reading Sl/Xl
    // ---- feats (+bias) -> Sl cols {w*32..w*32+31}, all rows ----
#pragma unroll
    for (int ct = 0; ct < 4; ++ct)
#pragma unroll
        for (int nt2 = 0; nt2 < 2; ++nt2) {
            int j = (w * 2 + nt2) * 16 + ln;
            float bj = cqab[j];
#pragma unroll
            for (int r = 0; r < 4; ++r) Sl[(ct * 16 + quad * 4 + r) * 136 + j] = f2b(accF[ct][nt2][r] + bj);
        }
    __syncthreads();  // barrier3: feats complete
    // ---- out = relu(feats @ ccW[:, :128].T + pc), N-split: wave w -> ot {2w, 2w+1} ----
    float4v accO[4][2];
#pragma unroll
    for (int ct = 0; ct < 4; ++ct)
#pragma unroll
        for (int ot2 = 0; ot2 < 2; ++ot2) accO[ct][ot2] = (float4v){0.f, 0.f, 0.f, 0.f};
#pragma unroll
    for (int ks = 0; ks < 4; ++ks) {
        short8 a[4];
#pragma unroll
        for (int ct = 0; ct < 4; ++ct) a[ct] = *(const short8*)(Sl + (ct * 16 + ln) * 136 + ks * 32 + quad * 8);
#pragma unroll
        for (int ot2 = 0; ot2 < 2; ++ot2) {
            short8 bw = *(const short8*)(ccWp + (((size_t)((w * 2 + ot2) * 4 + ks)) << 9) + lane * 8);
#pragma unroll
            for (int ct = 0; ct < 4; ++ct) accO[ct][ot2] = MFMA16(a[ct], bw, accO[ct][ot2]);
        }
    }
#pragma unroll
    for (int ct = 0; ct < 4; ++ct)
#pragma unroll
        for (int ot2 = 0; ot2 < 2; ++ot2) {
            int o = (w * 2 + ot2) * 16 + ln;
            float pco = pc[b * 128 + o];
#pragma unroll
            for (int r = 0; r < 4; ++r) {
                int c = cx * 64 + ct * 16 + quad * 4 + r;
                out[((size_t)(b * 2048 + c) << 7) + o] = fmaxf(accO[ct][ot2][r] + pco, 0.f);
            }
        }
}

extern "C" void kernel_launch(void* const* d_in, const int* in_sizes, int n_in, void* d_out, int out_size, void* d_ws,
                              size_t ws_size, hipStream_t stream) {
    const float* vf = (const float*)d_in[0];
    const float* qf = (const float*)d_in[1];
    const float* vmask = (const float*)d_in[2];
    const float* qmask = (const float*)d_in[3];
    const float* w4C = (const float*)d_in[4];
    const float* w4Q = (const float*)d_in[5];
    const float* w4mlu = (const float*)d_in[6];
    const float* cqaW = (const float*)d_in[7];
    const float* cqab = (const float*)d_in[8];
    const float* wp = (const float*)d_in[9];
    const float* ccW = (const float*)d_in[10];
    const float* ccb = (const float*)d_in[11];
    float* out = (float*)d_out;
    char* ws = (char*)d_ws;

    // workspace layout (~83 MB)
    size_t o = 0;
    short* vfA = (short*)(ws + o); o += 64ull * 2048 * 128 * 2;   // 33.5 MB
    short* vfT = (short*)(ws + o); o += 64ull * 2048 * 128 * 2;   // 33.5 MB
    short* qfBW = (short*)(ws + o); o += 64ull * 128 * 128 * 2;   // 2 MB
    short* qTf = (short*)(ws + o); o += 64ull * 128 * 128 * 2;    // 2 MB
    short* Ttf = (short*)(ws + o); o += 64ull * 128 * 128 * 2;    // 2 MB
    short* cqaWp = (short*)(ws + o); o += 128ull * 512 * 2;       // 128 KB
    short* ccWp = (short*)(ws + o); o += 128ull * 128 * 2;        // 32 KB
    float* Pg = (float*)(ws + o); o += 2ull * 64 * 128 * 128 * 4; // 8.4 MB
    float* Csg = (float*)(ws + o); o += 2ull * 64 * 128 * 4;      // 64 KB
    float* cvp = (float*)(ws + o); o += 64ull * 2048 * 4;         // 512 KB
    float* qvp = (float*)(ws + o); o += 64ull * 128 * 4;
    float* pc = (float*)(ws + o); o += 64ull * 128 * 4;

    k_packfuse<<<dim3(64, 64), 256, 0, stream>>>(vf, nullptr, w4C, vmask, vfA, vfT, cvp, 64);
    k_packfuse<<<dim3(4, 64), 256, 0, stream>>>(qf, w4mlu, w4Q, qmask, qfBW, qTf, qvp, 4);
    k_packW<<<32, 256, 0, stream>>>(cqaW, cqaWp);
    k_packWc<<<8, 256, 0, stream>>>(ccW, ccWp);
    k_pool<<<64, 128, 0, stream>>>(qf, qmask, wp, ccW, ccb, pc);
    k_Tacc<<<1024, 256, 0, stream>>>(vfA, vfT, qfBW, cvp, Pg, Csg);
    k_Tcomb<<<512, 256, 0, stream>>>(Pg, Csg, Ttf);
    k_out<<<2048, 256, 0, stream>>>(vfA, qfBW, qTf, Ttf, qvp, cqaWp, cqab, ccWp, pc, out);
}